// Round 7
// baseline (191.258 us; speedup 1.0000x reference)
//
#include <hip/hip_runtime.h>
#include <math.h>

#define BLOCK 256
#define VEC   4
#define TILE  (BLOCK * VEC)      // 1024 elements per tile
#define KW    5
#define TPB   5                  // tiles per block (10 tiles/row -> 2 blocks/row)
// conv pad = 2 each; two stacked convs -> receptive field of out[i] is x[i-4 .. i+4].
// Each thread computes 4 outputs from x[i-4 .. i+7] (three aligned float4 loads).
// Software pipeline: issue tile t+1's loads before computing tile t, so each
// wave always has global loads in flight under the ~400cy compute. No LDS.

typedef float f32x4 __attribute__((ext_vector_type(4)));

__device__ __forceinline__ void load_tile(const float* __restrict__ xr,
                                          int i, int L, float a[12]) {
    if (i >= 4 && i + 7 < L) {
        // i is a multiple of 4 -> all three loads are 16B-aligned, lane-contiguous
        f32x4 v0 = *reinterpret_cast<const f32x4*>(xr + i - 4);
        f32x4 v1 = *reinterpret_cast<const f32x4*>(xr + i);
        f32x4 v2 = *reinterpret_cast<const f32x4*>(xr + i + 4);
        #pragma unroll
        for (int e = 0; e < 4; ++e) {
            a[e] = v0[e]; a[4 + e] = v1[e]; a[8 + e] = v2[e];
        }
    } else {
        #pragma unroll
        for (int e = 0; e < 12; ++e) {
            int g = i - 4 + e;
            a[e] = (g >= 0 && g < L) ? xr[g] : 0.f;
        }
    }
}

__device__ __forceinline__ void compute_store(const float a[12], int i, int L,
                                              const float* W1, float B1,
                                              const float* W2, float B2,
                                              float* __restrict__ outr) {
    // h[j] = LeakyReLU(conv1)(x) at p = i + j - 2; conv2 zero-pads h outside [0,L)
    float h[8];
    #pragma unroll
    for (int j = 0; j < 8; ++j) {
        int p = i + j - 2;
        float acc = B1;
        #pragma unroll
        for (int k = 0; k < KW; ++k)
            acc = fmaf(W1[k], a[j + k], acc);
        acc = (acc >= 0.f) ? acc : 0.01f * acc;
        h[j] = (p >= 0 && p < L) ? acc : 0.f;
    }
    float res[4];
    #pragma unroll
    for (int e = 0; e < 4; ++e) {
        float z = B2;
        #pragma unroll
        for (int k = 0; k < KW; ++k)
            z = fmaf(W2[k], h[e + k], z);
        float s = __builtin_amdgcn_rcpf(1.f + __expf(-z));
        res[e] = a[4 + e] * s;
    }
    if (i + 3 < L) {
        f32x4 r = { res[0], res[1], res[2], res[3] };
        *reinterpret_cast<f32x4*>(outr + i) = r;
    } else {
        #pragma unroll
        for (int e = 0; e < 4; ++e)
            if (i + e < L) outr[i + e] = res[e];
    }
}

__global__ __launch_bounds__(BLOCK) void wav_attn_kernel(
    const float* __restrict__ x,
    const float* __restrict__ w1,
    const float* __restrict__ b1,
    const float* __restrict__ w2,
    const float* __restrict__ b2,
    float* __restrict__ out,
    int C, int L)
{
    const int row = blockIdx.y;            // b*C + c
    const int c   = row % C;
    const float* xr   = x   + (long long)row * L;
    float*       outr = out + (long long)row * L;

    // per-channel weights: block-uniform address -> scalar (s_load) path
    float W1[KW], W2[KW];
    #pragma unroll
    for (int k = 0; k < KW; ++k) {
        W1[k] = w1[c * KW + k];
        W2[k] = w2[c * KW + k];
    }
    const float B1 = b1[c];
    const float B2 = b2[c];

    int i = (blockIdx.x * TPB) * TILE + threadIdx.x * VEC;

    float aCur[12], aNxt[12] = {};
    load_tile(xr, i, L, aCur);

    #pragma unroll
    for (int t = 0; t < TPB; ++t) {
        const int iN = i + TILE;
        if (t + 1 < TPB)
            load_tile(xr, iN, L, aNxt);      // next tile's loads in flight...
        if (i < L)
            compute_store(aCur, i, L, W1, B1, W2, B2, outr);  // ...under this
        #pragma unroll
        for (int e = 0; e < 12; ++e) aCur[e] = aNxt[e];
        i = iN;
    }
}

extern "C" void kernel_launch(void* const* d_in, const int* in_sizes, int n_in,
                              void* d_out, int out_size, void* d_ws, size_t ws_size,
                              hipStream_t stream) {
    const float* x  = (const float*)d_in[0];
    const float* w1 = (const float*)d_in[1];
    const float* b1 = (const float*)d_in[2];
    const float* w2 = (const float*)d_in[3];
    const float* b2 = (const float*)d_in[4];
    float* out = (float*)d_out;

    const int C = in_sizes[2];               // 20
    const int B = 128;
    const int L = in_sizes[0] / (B * C);     // 10000

    const int nTiles = (L + TILE - 1) / TILE;          // 10
    dim3 grid((nTiles + TPB - 1) / TPB, B * C);        // 2 x 2560 = 5120 blocks
    wav_attn_kernel<<<grid, BLOCK, 0, stream>>>(x, w1, b1, w2, b2, out, C, L);
}

// Round 10
// 181.405 us; speedup vs baseline: 1.0543x; 1.0543x over previous
//
#include <hip/hip_runtime.h>
#include <math.h>

#define BLOCK 256
#define VEC   4
#define TILE  (BLOCK * VEC)   // 1024 elements per block
#define KW    5
// conv pad = 2 each; two stacked convs -> receptive field of out[i] is x[i-4 .. i+4].
// One tile per thread (short waves => high TLP). Interior blocks (1..last-1) take a
// check-free path; only edge blocks pay boundary machinery. No LDS, no barriers.

typedef float f32x4 __attribute__((ext_vector_type(4)));

__global__ __launch_bounds__(BLOCK) void wav_attn_kernel(
    const float* __restrict__ x,
    const float* __restrict__ w1,
    const float* __restrict__ b1,
    const float* __restrict__ w2,
    const float* __restrict__ b2,
    float* __restrict__ out,
    int C, int L)
{
    const int row = blockIdx.y;          // b*C + c
    const int c   = row % C;
    const float* xr   = x   + (long long)row * L;
    float*       outr = out + (long long)row * L;

    // per-channel weights: block-uniform address -> scalar (s_load) path
    float W1[KW], W2[KW];
    #pragma unroll
    for (int k = 0; k < KW; ++k) {
        W1[k] = w1[c * KW + k];
        W2[k] = w2[c * KW + k];
    }
    const float B1 = b1[c];
    const float B2 = b2[c];

    const int i = blockIdx.x * TILE + threadIdx.x * VEC;
    const int lastBlk = gridDim.x - 1;

    if (blockIdx.x != 0 && blockIdx.x != lastBlk) {
        // ---- interior fast path: i-4 >= 0 and i+7 < L guaranteed; no clamps ----
        f32x4 v0 = *reinterpret_cast<const f32x4*>(xr + i - 4);
        f32x4 v1 = *reinterpret_cast<const f32x4*>(xr + i);
        f32x4 v2 = *reinterpret_cast<const f32x4*>(xr + i + 4);
        float a[12];
        #pragma unroll
        for (int e = 0; e < 4; ++e) {
            a[e] = v0[e]; a[4 + e] = v1[e]; a[8 + e] = v2[e];
        }

        float h[8];
        #pragma unroll
        for (int j = 0; j < 8; ++j) {
            float acc = B1;
            #pragma unroll
            for (int k = 0; k < KW; ++k)
                acc = fmaf(W1[k], a[j + k], acc);
            h[j] = (acc >= 0.f) ? acc : 0.01f * acc;   // interior: never outside [0,L)
        }

        float res[4];
        #pragma unroll
        for (int e = 0; e < 4; ++e) {
            float z = B2;
            #pragma unroll
            for (int k = 0; k < KW; ++k)
                z = fmaf(W2[k], h[e + k], z);
            float s = __builtin_amdgcn_rcpf(1.f + __expf(-z));
            res[e] = a[4 + e] * s;
        }
        f32x4 r = { res[0], res[1], res[2], res[3] };
        *reinterpret_cast<f32x4*>(outr + i) = r;
    } else {
        // ---- edge path: full boundary handling ----
        if (i >= L) return;

        float a[12];
        if (i >= 4 && i + 7 < L) {
            f32x4 v0 = *reinterpret_cast<const f32x4*>(xr + i - 4);
            f32x4 v1 = *reinterpret_cast<const f32x4*>(xr + i);
            f32x4 v2 = *reinterpret_cast<const f32x4*>(xr + i + 4);
            #pragma unroll
            for (int e = 0; e < 4; ++e) {
                a[e] = v0[e]; a[4 + e] = v1[e]; a[8 + e] = v2[e];
            }
        } else {
            #pragma unroll
            for (int e = 0; e < 12; ++e) {
                int g = i - 4 + e;
                a[e] = (g >= 0 && g < L) ? xr[g] : 0.f;
            }
        }

        // h at p = i + j - 2; conv2's zero-padding applies to h outside [0,L)
        float h[8];
        #pragma unroll
        for (int j = 0; j < 8; ++j) {
            int p = i + j - 2;
            float acc = B1;
            #pragma unroll
            for (int k = 0; k < KW; ++k)
                acc = fmaf(W1[k], a[j + k], acc);
            acc = (acc >= 0.f) ? acc : 0.01f * acc;
            h[j] = (p >= 0 && p < L) ? acc : 0.f;
        }

        float res[4];
        #pragma unroll
        for (int e = 0; e < 4; ++e) {
            float z = B2;
            #pragma unroll
            for (int k = 0; k < KW; ++k)
                z = fmaf(W2[k], h[e + k], z);
            float s = __builtin_amdgcn_rcpf(1.f + __expf(-z));
            res[e] = a[4 + e] * s;
        }
        if (i + 3 < L) {
            f32x4 r = { res[0], res[1], res[2], res[3] };
            *reinterpret_cast<f32x4*>(outr + i) = r;
        } else {
            #pragma unroll
            for (int e = 0; e < 4; ++e)
                if (i + e < L) outr[i + e] = res[e];
        }
    }
}

extern "C" void kernel_launch(void* const* d_in, const int* in_sizes, int n_in,
                              void* d_out, int out_size, void* d_ws, size_t ws_size,
                              hipStream_t stream) {
    const float* x  = (const float*)d_in[0];
    const float* w1 = (const float*)d_in[1];
    const float* b1 = (const float*)d_in[2];
    const float* w2 = (const float*)d_in[3];
    const float* b2 = (const float*)d_in[4];
    float* out = (float*)d_out;

    const int C = in_sizes[2];               // 20
    const int B = 128;
    const int L = in_sizes[0] / (B * C);     // 10000

    dim3 grid((L + TILE - 1) / TILE, B * C); // 10 x 2560 blocks
    wav_attn_kernel<<<grid, BLOCK, 0, stream>>>(x, w1, b1, w2, b2, out, C, L);
}